// Round 11
// baseline (40.974 us; speedup 1.0000x reference)
//
#include <hip/hip_runtime.h>
#include <cmath>

#define EPSN 1e-12f

typedef _Float16 half8 __attribute__((ext_vector_type(8)));
typedef float f32x4 __attribute__((ext_vector_type(4)));

// ---------------------------------------------------------------------------
// scores_kernel: one block per (b, n, quarter) = 64 doc tokens; grid 4096.
// 256 threads = 4 waves. Mask-compacted (r10-validated semantics: pad slots
// inject sim=0 exactly when masked tokens exist). Thread (s=t>>2, kq=t&3)
// owns K-slice [32kq,32kq+32) of token compactS[s]: 8 contiguous float4
// loads issued at once; single stage phase builds full-K B-image (32 KB);
// single MFMA phase (wave w owns token tile w, 24 MFMA). 3 barriers total.
// All numeric paths (CVT hi/lo, A/B fragment layouts, 3-term MFMA, epilogue
// mapping) are r4-exact.
// ---------------------------------------------------------------------------
__global__ __launch_bounds__(256, 3) void scores_kernel(
    const float* __restrict__ qr, const float* __restrict__ doc,
    const int* __restrict__ mask, float* __restrict__ pmax) {
    __shared__ __align__(16) char Aimg[16384];   // [qt2][kstep4][hl2][1024B]
    __shared__ __align__(16) char Bimg[32768];   // [tile4][kq4][hl2][quad4*16+col][16B]
    __shared__ float invS[64];
    __shared__ int   compactS[64];
    __shared__ int   cntS;
    __shared__ float wq[4][32];

    int t = threadIdx.x, g = blockIdx.x;
    int bn = g >> 2, q4 = g & 3, b = g >> 6;
    int w = t >> 6, lane = t & 63, col = lane & 15;

    // ---- q loads first (arrive during compaction) ----
    int row = t >> 3, jb = t & 7;
    const float4* qsrc = (const float4*)(qr + ((size_t)b * 32 + row) * 128 + jb * 16);
    float4 v0 = qsrc[0], v1 = qsrc[1], v2 = qsrc[2], v3 = qsrc[3];

    // ---- mask + ballot compaction over this quarter's 64 tokens (wave 0) ----
    int myMask = 0;
    if (t < 64) myMask = mask[bn * 256 + q4 * 64 + t];
    unsigned long long bal = __ballot(myMask != 0);
    if (t == 0) cntS = __popcll(bal);
    if (myMask) {                                 // only t<64 can be true
        int prefix = __popcll(bal & ((1ull << lane) - 1));
        compactS[prefix] = t;
    }
    __syncthreads();                              // barrier 1
    int cnt = cntS;
    int s = t >> 2, kq = t & 3;
    bool real = (s < cnt);
    int tokc = real ? compactS[s] : 0;

    // ---- issue all 8 doc loads at once (deep MLP; exec-masked if pad) ----
    const float4* dsrc = (const float4*)(doc + ((size_t)bn * 256 + q4 * 64 + tokc) * 128) + kq * 8;
    float4 r0, r1, r2, r3, r4, r5, r6, r7;
    if (real) {
        r0 = dsrc[0]; r1 = dsrc[1]; r2 = dsrc[2]; r3 = dsrc[3];
        r4 = dsrc[4]; r5 = dsrc[5]; r6 = dsrc[6]; r7 = dsrc[7];
    }

    // ---- A-image build (r4-exact; overlaps doc load latency) ----
    {
        float ss = v0.x*v0.x + v0.y*v0.y + v0.z*v0.z + v0.w*v0.w
                 + v1.x*v1.x + v1.y*v1.y + v1.z*v1.z + v1.w*v1.w
                 + v2.x*v2.x + v2.y*v2.y + v2.z*v2.z + v2.w*v2.w
                 + v3.x*v3.x + v3.y*v3.y + v3.z*v3.z + v3.w*v3.w;
        ss += __shfl_xor(ss, 1); ss += __shfl_xor(ss, 2); ss += __shfl_xor(ss, 4);
        float inv = 1.0f / fmaxf(sqrtf(ss), EPSN);
        int qt = row >> 4, kstep = jb >> 1;
        float4 vv[4] = { v0, v1, v2, v3 };
#pragma unroll
        for (int khh = 0; khh < 2; ++khh) {
            float xs[8] = { vv[2*khh].x,   vv[2*khh].y,   vv[2*khh].z,   vv[2*khh].w,
                            vv[2*khh+1].x, vv[2*khh+1].y, vv[2*khh+1].z, vv[2*khh+1].w };
            half8 hh, hl;
#pragma unroll
            for (int e = 0; e < 8; ++e) {
                float x = xs[e] * inv;
                _Float16 hv = (_Float16)x;
                hh[e] = hv;
                hl[e] = (_Float16)(x - (float)hv);
            }
            int quad = (jb & 1) * 2 + khh;
            int base = ((qt * 4 + kstep) * 2) * 1024 + ((row & 15) + quad * 16) * 16;
            *(half8*)(Aimg + base)        = hh;
            *(half8*)(Aimg + base + 1024) = hl;
        }
    }

    // ---- stage phase: full K=128 B-image + invS (single phase) ----
    int tileS = s >> 4, colS = s & 15;
    int bo0 = tileS * 8192 + kq * 2048 + colS * 16;
    float ss_d = 0.f;
    if (real) {
        ss_d = r0.x*r0.x + r0.y*r0.y + r0.z*r0.z + r0.w*r0.w
             + r1.x*r1.x + r1.y*r1.y + r1.z*r1.z + r1.w*r1.w
             + r2.x*r2.x + r2.y*r2.y + r2.z*r2.z + r2.w*r2.w
             + r3.x*r3.x + r3.y*r3.y + r3.z*r3.z + r3.w*r3.w
             + r4.x*r4.x + r4.y*r4.y + r4.z*r4.z + r4.w*r4.w
             + r5.x*r5.x + r5.y*r5.y + r5.z*r5.z + r5.w*r5.w
             + r6.x*r6.x + r6.y*r6.y + r6.z*r6.z + r6.w*r6.w
             + r7.x*r7.x + r7.y*r7.y + r7.z*r7.z + r7.w*r7.w;
#define CVTQ(PA, PB, QD) do {                                                 \
        float xs[8] = { PA.x, PA.y, PA.z, PA.w, PB.x, PB.y, PB.z, PB.w };     \
        half8 hh, hl;                                                         \
        _Pragma("unroll")                                                     \
        for (int e = 0; e < 8; ++e) {                                         \
            float x = xs[e]; _Float16 hv = (_Float16)x;                       \
            hh[e] = hv; hl[e] = (_Float16)(x - (float)hv);                    \
        }                                                                     \
        *(half8*)(Bimg + bo0 + (QD) * 256)        = hh;                       \
        *(half8*)(Bimg + bo0 + (QD) * 256 + 1024) = hl;                       \
    } while (0)
        CVTQ(r0, r1, 0); CVTQ(r2, r3, 1); CVTQ(r4, r5, 2); CVTQ(r6, r7, 3);
#undef CVTQ
    } else {
        half8 hz = {0,0,0,0,0,0,0,0};
#pragma unroll
        for (int qd = 0; qd < 4; ++qd) {
            *(half8*)(Bimg + bo0 + qd * 256)        = hz;
            *(half8*)(Bimg + bo0 + qd * 256 + 1024) = hz;
        }
    }
    ss_d += __shfl_xor(ss_d, 1); ss_d += __shfl_xor(ss_d, 2);   // 4 lanes/token
    if (kq == 0) invS[s] = real ? (1.0f / fmaxf(sqrtf(ss_d), EPSN)) : 0.0f;

    asm volatile("s_waitcnt lgkmcnt(0)" ::: "memory");
    __builtin_amdgcn_s_barrier();                 // barrier 2

    // ---- MFMA phase: wave w owns token tile w; 4 ksteps x 3-term x 2 qt ----
    f32x4 acc0 = {0.f, 0.f, 0.f, 0.f};
    f32x4 acc1 = {0.f, 0.f, 0.f, 0.f};
    int lo = lane << 4;
#pragma unroll
    for (int k2 = 0; k2 < 4; ++k2) {
        half8 a0h = *(const half8*)(Aimg + ((0 * 4 + k2) * 2 + 0) * 1024 + lo);
        half8 a0l = *(const half8*)(Aimg + ((0 * 4 + k2) * 2 + 1) * 1024 + lo);
        half8 a1h = *(const half8*)(Aimg + ((1 * 4 + k2) * 2 + 0) * 1024 + lo);
        half8 a1l = *(const half8*)(Aimg + ((1 * 4 + k2) * 2 + 1) * 1024 + lo);
        half8 bh  = *(const half8*)(Bimg + w * 8192 + k2 * 2048 + lo);
        half8 bl  = *(const half8*)(Bimg + w * 8192 + k2 * 2048 + 1024 + lo);
        acc0 = __builtin_amdgcn_mfma_f32_16x16x32_f16(a0l, bh, acc0, 0, 0, 0);
        acc0 = __builtin_amdgcn_mfma_f32_16x16x32_f16(a0h, bl, acc0, 0, 0, 0);
        acc0 = __builtin_amdgcn_mfma_f32_16x16x32_f16(a0h, bh, acc0, 0, 0, 0);
        acc1 = __builtin_amdgcn_mfma_f32_16x16x32_f16(a1l, bh, acc1, 0, 0, 0);
        acc1 = __builtin_amdgcn_mfma_f32_16x16x32_f16(a1h, bl, acc1, 0, 0, 0);
        acc1 = __builtin_amdgcn_mfma_f32_16x16x32_f16(a1h, bh, acc1, 0, 0, 0);
    }

    // ---- epilogue: inv-norm, max over wave's 16 tokens (r4-exact mapping) ----
    float inv = invS[w * 16 + col];
    float m8[8];
#pragma unroll
    for (int rr = 0; rr < 4; ++rr) {
        m8[rr]     = acc0[rr] * inv;
        m8[4 + rr] = acc1[rr] * inv;
    }
#pragma unroll
    for (int off = 1; off < 16; off <<= 1)
#pragma unroll
        for (int i = 0; i < 8; ++i) m8[i] = fmaxf(m8[i], __shfl_xor(m8[i], off));
    if (col == 0) {
        int rg = lane >> 4;   // C/D: row = (lane>>4)*4 + reg (m89-verified)
#pragma unroll
        for (int rr = 0; rr < 4; ++rr) {
            wq[w][rg * 4 + rr]      = m8[rr];
            wq[w][16 + rg * 4 + rr] = m8[4 + rr];
        }
    }
    __syncthreads();                              // barrier 3
    if (w == 0 && lane < 32) {
        float v = fmaxf(fmaxf(wq[0][lane], wq[1][lane]), fmaxf(wq[2][lane], wq[3][lane]));
        pmax[(size_t)g * 32 + lane] = v;
    }
}

// ---------------------------------------------------------------------------
// lossb_kernel: one block per b. Reads its 8 KB pmax slice (64 quarter-rows),
// combines 4 quarters per n into scores, 256 pair losses -> partial[b].
// ---------------------------------------------------------------------------
__global__ __launch_bounds__(256) void lossb_kernel(const float* __restrict__ pmax,
                                                    const float* __restrict__ labels,
                                                    float* __restrict__ partial) {
    __shared__ float pmL[2048];
    __shared__ float sc[16], ysS[16], idxS[16];
    __shared__ float wsum[4];
    int b = blockIdx.x, t = threadIdx.x;
    ((float4*)pmL)[t]       = ((const float4*)(pmax + (size_t)b * 2048))[t];
    ((float4*)pmL)[t + 256] = ((const float4*)(pmax + (size_t)b * 2048))[t + 256];
    if (t < 16) { ysS[t] = labels[b * 32 + t]; idxS[t] = labels[b * 32 + 16 + t]; }
    __syncthreads();
    {
        int n = t >> 4, qq = t & 15;
        // rows (n*4+qt)*32 + q, qt = quarter
        float ma = fmaxf(fmaxf(pmL[(n * 4 + 0) * 32 + qq],      pmL[(n * 4 + 1) * 32 + qq]),
                         fmaxf(pmL[(n * 4 + 2) * 32 + qq],      pmL[(n * 4 + 3) * 32 + qq]));
        float mb = fmaxf(fmaxf(pmL[(n * 4 + 0) * 32 + 16 + qq], pmL[(n * 4 + 1) * 32 + 16 + qq]),
                         fmaxf(pmL[(n * 4 + 2) * 32 + 16 + qq], pmL[(n * 4 + 3) * 32 + 16 + qq]));
        float v = ma + mb;
        v += __shfl_xor(v, 1); v += __shfl_xor(v, 2);
        v += __shfl_xor(v, 4); v += __shfl_xor(v, 8);
        if (qq == 0) sc[n] = v;
    }
    __syncthreads();
    int i = t >> 4, j = t & 15;
    float v = 0.f;
    if (ysS[i] - ysS[j] > 0.f) {
        float wgt = fabsf(idxS[i] - idxS[j]);
        float d = (i <= j) ? (sc[i] - sc[j]) : 0.f;
        v = log1pf(expf(-d)) * wgt;
    }
#pragma unroll
    for (int off = 1; off < 64; off <<= 1) v += __shfl_xor(v, off);
    int lane = t & 63;
    if (lane == 0) wsum[t >> 6] = v;
    __syncthreads();
    if (t == 0) partial[b] = wsum[0] + wsum[1] + wsum[2] + wsum[3];
}

__global__ void lossfin_kernel(const float* __restrict__ partial, float* __restrict__ out) {
    int t = threadIdx.x;   // 64 threads, one wave
    float v = partial[t];
#pragma unroll
    for (int off = 1; off < 64; off <<= 1) v += __shfl_xor(v, off);
    if (t == 0) out[0] = v;
}

// ---------------------------------------------------------------------------
extern "C" void kernel_launch(void* const* d_in, const int* in_sizes, int n_in,
                              void* d_out, int out_size, void* d_ws, size_t ws_size,
                              hipStream_t stream) {
    const float* qr     = (const float*)d_in[0];   // (64,32,128) f32
    const float* doc    = (const float*)d_in[1];   // (64,16,256,128) f32
    const int*   dmask  = (const int*)d_in[2];     // (64,16,256) i32
    const float* labels = (const float*)d_in[3];   // (64,32) f32
    float* out = (float*)d_out;

    float* pmax    = (float*)d_ws;                 // 4096*32 f32 = 512 KB
    float* partial = pmax + 4096 * 32;             // 64 f32

    scores_kernel<<<4096, 256, 0, stream>>>(qr, doc, dmask, pmax);
    lossb_kernel<<<64, 256, 0, stream>>>(pmax, labels, partial);
    lossfin_kernel<<<1, 64, 0, stream>>>(partial, out);
}